// Round 8
// baseline (309.739 us; speedup 1.0000x reference)
//
#include <hip/hip_runtime.h>
#include <cstddef>

#define B_ 64
#define T_ 1000
#define F_ 512
#define H_ 8
#define KD_ 32
#define HK_ 256   // H_*KD_
#define NC_ 8     // t-chunks
#define CT_ 125   // rows per chunk (8*125 = 1000)

// ---------------- K1: qh[h,k] = sum_f q[f]*Wq[f,h,k] + bq[h,k] ----------------
__global__ __launch_bounds__(64) void k_qh(const float* __restrict__ q,
                                           const float* __restrict__ Wq,
                                           const float* __restrict__ bq,
                                           float* __restrict__ qh) {
    int hk = blockIdx.x;           // 0..255
    int lane = threadIdx.x;        // 0..63
    float s = 0.f;
    for (int f = lane; f < F_; f += 64) s += q[f] * Wq[(size_t)f * HK_ + hk];
    #pragma unroll
    for (int off = 32; off; off >>= 1) s += __shfl_down(s, off);
    if (lane == 0) qh[hk] = s + bq[hk];
}

// ---------------- K2: wk[f,h] = sum_k qh[h,k]*Wk[f,h,k]; ck[h] = qh[h,:].bk[h,:] ----------------
__global__ __launch_bounds__(256) void k_wk(const float* __restrict__ qh,
                                            const float* __restrict__ Wk,
                                            const float* __restrict__ bk,
                                            float* __restrict__ wk,
                                            float* __restrict__ ck) {
    int f = blockIdx.x;            // 0..511
    int tid = threadIdx.x;         // tid = h*32+k
    __shared__ float red[256];
    red[tid] = qh[tid] * Wk[(size_t)f * HK_ + tid];
    __syncthreads();
    #pragma unroll
    for (int off = 16; off; off >>= 1) {
        if ((tid & 31) < off) red[tid] += red[tid + off];
        __syncthreads();
    }
    if ((tid & 31) == 0) wk[f * H_ + (tid >> 5)] = red[tid];
    if (f == 0 && tid < H_) {
        float c = 0.f;
        for (int k = 0; k < KD_; k++) c += qh[tid * KD_ + k] * bk[tid * KD_ + k];
        ck[tid] = c;
    }
}

// ---------------- K3: fused chunk kernel, 512 threads ----------------
// phase1: 8 waves = (2 row-halves) x (4 f-quarters); wk wave-uniform -> s_load.
// phase2: wave-per-head chunk-local softmax. phase3: thread-per-f weighted sum.
__global__ __launch_bounds__(512) void k_fused(const float* __restrict__ x,
                                               const float* __restrict__ wk,
                                               const float* __restrict__ ck,
                                               float* __restrict__ part,
                                               float2* __restrict__ ml2) {
    __shared__ float atp[128][4][H_ + 1];   // 18 KB (padded): per-quarter partial scores
    __shared__ float at[128][H_];           // 4 KB: scores -> p values
    const int c = blockIdx.x & (NC_ - 1);
    const int b = blockIdx.x >> 3;
    const int tid = threadIdx.x;
    const int lane = tid & 63;
    const int w = __builtin_amdgcn_readfirstlane(tid >> 6);  // wave id 0..7 (uniform)
    const int qw = w & 3, rh = w >> 2;
    const int row = rh * 64 + lane;
    const float scale = 0.17677669529663687f;  // 1/sqrt(32)

    // ---- phase 1: partial scores; wave covers f in [qw*128, qw*128+128) ----
    if (row < CT_) {
        float acc[H_] = {0.f,0.f,0.f,0.f,0.f,0.f,0.f,0.f};
        const float4* xr = (const float4*)(x + ((size_t)b * T_ + (size_t)c * CT_ + row) * F_) + qw * 32;
        const float* wkq = wk + qw * 128 * H_;
        for (int ii = 0; ii < 4; ii++) {
            float4 xv[8];
            #pragma unroll
            for (int u = 0; u < 8; u++) xv[u] = xr[ii * 8 + u];
            #pragma unroll
            for (int u = 0; u < 8; u++) {
                const float* wr = wkq + (ii * 8 + u) * 32;   // wave-uniform -> s_load
                #pragma unroll
                for (int h = 0; h < H_; h++)
                    acc[h] += xv[u].x * wr[h]      + xv[u].y * wr[8 + h]
                            + xv[u].z * wr[16 + h] + xv[u].w * wr[24 + h];
            }
        }
        #pragma unroll
        for (int h = 0; h < H_; h++) atp[row][qw][h] = acc[h];
    }
    __syncthreads();

    // ---- combine quarters ----
    for (int i = tid; i < CT_ * H_; i += 512) {
        int r = i >> 3, h = i & 7;
        at[r][h] = (atp[r][0][h] + atp[r][1][h] + atp[r][2][h] + atp[r][3][h] + ck[h]) * scale;
    }
    __syncthreads();

    // ---- phase 2: chunk-local softmax, one wave per head ----
    {
        const int h = w;
        const int t1 = lane + 64;
        float s0 = (lane < CT_) ? at[lane][h] : -3.0e38f;
        float s1 = (t1 < CT_) ? at[t1][h] : -3.0e38f;
        float m = fmaxf(s0, s1);
        #pragma unroll
        for (int off = 32; off; off >>= 1) m = fmaxf(m, __shfl_xor(m, off));
        float p0 = (lane < CT_) ? __expf(s0 - m) : 0.f;
        float p1 = (t1 < CT_) ? __expf(s1 - m) : 0.f;
        if (lane < CT_) at[lane][h] = p0;
        if (t1 < CT_) at[t1][h] = p1;
        float l = p0 + p1;
        #pragma unroll
        for (int off = 32; off; off >>= 1) l += __shfl_xor(l, off);
        if (lane == 0) ml2[(size_t)(c * B_ + b) * H_ + h] = make_float2(m, l);
    }
    __syncthreads();

    // ---- phase 3: weighted partial sum, thread owns f = tid ----
    {
        const float* xc = x + ((size_t)b * T_ + (size_t)c * CT_) * F_ + tid;
        float a[H_] = {0.f,0.f,0.f,0.f,0.f,0.f,0.f,0.f};
        #pragma unroll 8
        for (int t = 0; t < CT_; t++) {
            const float xv = xc[(size_t)t * F_];
            #pragma unroll
            for (int h = 0; h < H_; h++) a[h] += at[t][h] * xv;   // uniform -> LDS broadcast
        }
        float* dst = part + (size_t)(c * B_ + b) * (H_ * F_) + tid;
        #pragma unroll
        for (int h = 0; h < H_; h++) dst[h * F_] = a[h];
    }
}

// ---------------- K4: ctx[b,hk] += sum_{f in quarter} xs[h,f]*Wv[f,hk]  (atomic over 4 f-quarters) ----------------
__global__ __launch_bounds__(256) void k_ctx(const float* __restrict__ part,
                                             const float2* __restrict__ ml2,
                                             const float* __restrict__ Wv,
                                             float* __restrict__ ctx) {
    __shared__ float coefL[NC_][H_];
    __shared__ float xsq[H_][132];    // padded (132%32=4) to spread banks
    const int b = blockIdx.x >> 2;
    const int fq = blockIdx.x & 3;
    const int tid = threadIdx.x;

    if (tid < 64) {
        const int c = tid >> 3, h = tid & 7;
        const float2 d = ml2[(size_t)(c * B_ + b) * H_ + h];
        float M = d.x;
        #pragma unroll
        for (int off = 8; off < 64; off <<= 1) M = fmaxf(M, __shfl_xor(M, off));
        const float e = __expf(d.x - M);
        float Lt = e * d.y;
        #pragma unroll
        for (int off = 8; off < 64; off <<= 1) Lt += __shfl_xor(Lt, off);
        coefL[c][h] = e / Lt;
    }
    __syncthreads();

    for (int i = tid; i < H_ * 128; i += 256) {
        const int h = i >> 7, fl = i & 127;
        float s = 0.f;
        #pragma unroll
        for (int c = 0; c < NC_; c++)
            s += coefL[c][h] * part[(size_t)(c * B_ + b) * (H_ * F_) + h * F_ + fq * 128 + fl];
        xsq[h][fl] = s;
    }
    __syncthreads();

    const int hk = tid, h = hk >> 5;
    float s = 0.f;
    #pragma unroll 8
    for (int j = 0; j < 128; j++)
        s += xsq[h][j] * Wv[(size_t)(fq * 128 + j) * HK_ + hk];
    atomicAdd(&ctx[(size_t)b * HK_ + hk], s);
}

// ---------------- K5: pooled = (ctx+bv)@Wo + bo; out = LN(pooled@Wd); 2 b-rows per block ----------------
__global__ __launch_bounds__(512) void k_out(const float* __restrict__ ctx,
                                             const float* __restrict__ bv,
                                             const float* __restrict__ Wo,
                                             const float* __restrict__ bo,
                                             const float* __restrict__ Wd,
                                             const float* __restrict__ gamma,
                                             const float* __restrict__ beta,
                                             float* __restrict__ out) {
    __shared__ float ctxL[2][HK_];
    __shared__ float pooledL[2][F_];
    __shared__ float red[32];
    __shared__ float stat[4];
    const int b0 = blockIdx.x * 2;
    const int tid = threadIdx.x;

    {
        const int r = tid >> 8, hk = tid & 255;
        ctxL[r][hk] = ctx[(size_t)(b0 + r) * HK_ + hk] + bv[hk];
    }
    __syncthreads();

    float p0 = bo[tid], p1 = p0;
    #pragma unroll 8
    for (int hk = 0; hk < HK_; hk++) {
        const float wo = Wo[(size_t)hk * F_ + tid];
        p0 += ctxL[0][hk] * wo;
        p1 += ctxL[1][hk] * wo;
    }
    pooledL[0][tid] = p0;
    pooledL[1][tid] = p1;
    __syncthreads();

    float o0 = 0.f, o1 = 0.f;
    #pragma unroll 8
    for (int g = 0; g < F_; g++) {
        const float wd = Wd[(size_t)g * F_ + tid];
        o0 += pooledL[0][g] * wd;
        o1 += pooledL[1][g] * wd;
    }

    {
        float v1 = o0, v2 = o0 * o0, v3 = o1, v4 = o1 * o1;
        #pragma unroll
        for (int off = 32; off; off >>= 1) {
            v1 += __shfl_down(v1, off);
            v2 += __shfl_down(v2, off);
            v3 += __shfl_down(v3, off);
            v4 += __shfl_down(v4, off);
        }
        const int lane = tid & 63, wid = tid >> 6;
        if (lane == 0) { red[wid * 4] = v1; red[wid * 4 + 1] = v2; red[wid * 4 + 2] = v3; red[wid * 4 + 3] = v4; }
        __syncthreads();
        if (tid == 0) {
            float s1 = 0.f, s2 = 0.f, s3 = 0.f, s4 = 0.f;
            #pragma unroll
            for (int ww = 0; ww < 8; ww++) {
                s1 += red[ww * 4]; s2 += red[ww * 4 + 1]; s3 += red[ww * 4 + 2]; s4 += red[ww * 4 + 3];
            }
            const float mu0 = s1 * (1.0f / F_), mu1 = s3 * (1.0f / F_);
            stat[0] = mu0;
            stat[1] = rsqrtf(s2 * (1.0f / F_) - mu0 * mu0 + 1e-6f);
            stat[2] = mu1;
            stat[3] = rsqrtf(s4 * (1.0f / F_) - mu1 * mu1 + 1e-6f);
        }
        __syncthreads();
    }
    const float g_ = gamma[tid], bt = beta[tid];
    out[(size_t)b0 * F_ + tid]       = (o0 - stat[0]) * stat[1] * g_ + bt;
    out[(size_t)(b0 + 1) * F_ + tid] = (o1 - stat[2]) * stat[3] * g_ + bt;
}

extern "C" void kernel_launch(void* const* d_in, const int* in_sizes, int n_in,
                              void* d_out, int out_size, void* d_ws, size_t ws_size,
                              hipStream_t stream) {
    const float* x     = (const float*)d_in[0];
    const float* q     = (const float*)d_in[1];
    const float* Wq    = (const float*)d_in[2];
    const float* bq    = (const float*)d_in[3];
    const float* Wk    = (const float*)d_in[4];
    const float* bk    = (const float*)d_in[5];
    const float* Wv    = (const float*)d_in[6];
    const float* bv    = (const float*)d_in[7];
    const float* Wo    = (const float*)d_in[8];
    const float* bo    = (const float*)d_in[9];
    const float* Wd    = (const float*)d_in[10];
    const float* gamma = (const float*)d_in[11];
    const float* beta  = (const float*)d_in[12];
    float* out = (float*)d_out;

    char* ws = (char*)d_ws;
    float*  qh   = (float*)(ws + 0);          // 1 KB
    float*  wk   = (float*)(ws + 4096);       // 16 KB  [f][h]
    float*  ck   = (float*)(ws + 20480);      // 32 B
    float2* ml2  = (float2*)(ws + 24576);     // 32 KB
    float*  ctx  = (float*)(ws + 65536);      // 64 KB
    float*  part = (float*)(ws + 1048576);    // 8 MB  [c][b][h][f]

    hipMemsetAsync(ctx, 0, B_ * HK_ * sizeof(float), stream);
    k_qh<<<HK_, 64, 0, stream>>>(q, Wq, bq, qh);
    k_wk<<<F_, 256, 0, stream>>>(qh, Wk, bk, wk, ck);
    k_fused<<<B_ * NC_, 512, 0, stream>>>(x, wk, ck, part, ml2);
    k_ctx<<<B_ * 4, 256, 0, stream>>>(part, ml2, Wv, ctx);
    k_out<<<B_ / 2, 512, 0, stream>>>(ctx, bv, Wo, bo, Wd, gamma, beta, out);
}